// Round 1
// baseline (427.264 us; speedup 1.0000x reference)
//
#include <hip/hip_runtime.h>
#include <hip/hip_bf16.h>

// Problem constants
#define NTOK 4096      // B*S
#define DIM  512       // D
#define DH   256       // D/2
#define NE   16        // experts
#define FF   2048      // F
#define CAP  8192      // per-expert list capacity
#define MAXTILES 80    // sum ceil(cnt_e/128) <= 79
#define TEMP_INV 2.0f  // 1/temperature

// out layout: [NTOK*DIM output][1 loss][NTOK*NE probs]
#define OUT_LOSS  (NTOK * DIM)
#define OUT_PROBS (NTOK * DIM + 1)

// ws layout (bytes)
#define WS_CNT    0            // int[16]
#define WS_USAGE  64           // float[16]
#define WS_NTILES 128          // int
#define WS_DESC   256          // int2[80]
#define WS_WTS    1024         // float[2*NTOK]
#define WS_LISTS  36864        // int[16*CAP]
#define WS_HID    (1u << 20)   // bf16 [80*128][FF]  (~40MB)
#define WS_PAIR   (48u << 20)  // float [2*NTOK][DIM] (16MB)

typedef __attribute__((ext_vector_type(8))) short bf16x8;           // MFMA A/B frag
typedef __attribute__((ext_vector_type(8))) unsigned short u16x8;   // 8 bf16 storage
typedef __attribute__((ext_vector_type(4))) float f32x4;            // MFMA C/D frag

__device__ __forceinline__ unsigned short f2bf(float f) {  // RNE f32->bf16
  union { float f; unsigned u; } c; c.f = f;
  return (unsigned short)((c.u + 0x7FFFu + ((c.u >> 16) & 1u)) >> 16);
}
__device__ __forceinline__ float gc(const float4& v, int c) {
  return c == 0 ? v.x : c == 1 ? v.y : c == 2 ? v.z : v.w;
}

// ---------------- router: fp32 gate MLP + softmax + top2 + lists ----------------
__launch_bounds__(256)
__global__ void router_kernel(const float* __restrict__ x,
                              const float* __restrict__ w1,
                              const float* __restrict__ b1,
                              const float* __restrict__ w2,
                              const float* __restrict__ b2,
                              float* __restrict__ out,
                              int* __restrict__ cnt,
                              float* __restrict__ usage,
                              float* __restrict__ wts,
                              int* __restrict__ lists) {
  __shared__ __align__(16) float xs[16][DIM];    // 32KB
  __shared__ __align__(16) float hs[16][DH + 4]; // padded
  __shared__ __align__(16) float w2s[DH * NE];
  __shared__ float ps[16][NE];

  int tid = threadIdx.x;
  int tok0 = blockIdx.x * 16;

  // stage x tile + w2
  {
    const float4* xg = (const float4*)(x + (size_t)tok0 * DIM);
    float4* xv = (float4*)&xs[0][0];
    for (int i = tid; i < 16 * DIM / 4; i += 256) xv[i] = xg[i];
    for (int i = tid; i < DH * NE; i += 256) w2s[i] = w2[i];
  }
  __syncthreads();

  // h = relu(x @ w1 + b1): thread j = tid computes column j for 16 tokens
  {
    int j = tid;
    float acc[16];
    float bj = b1[j];
#pragma unroll
    for (int t = 0; t < 16; ++t) acc[t] = bj;
    for (int k = 0; k < DIM; k += 4) {
      float wa = w1[(k + 0) * DH + j];
      float wb = w1[(k + 1) * DH + j];
      float wcv = w1[(k + 2) * DH + j];
      float wd = w1[(k + 3) * DH + j];
#pragma unroll
      for (int t = 0; t < 16; ++t) {
        float4 xv = *(const float4*)&xs[t][k];
        acc[t] = fmaf(xv.x, wa, acc[t]);
        acc[t] = fmaf(xv.y, wb, acc[t]);
        acc[t] = fmaf(xv.z, wcv, acc[t]);
        acc[t] = fmaf(xv.w, wd, acc[t]);
      }
    }
#pragma unroll
    for (int t = 0; t < 16; ++t) hs[t][j] = fmaxf(acc[t], 0.f);
  }
  __syncthreads();

  // scores + softmax: thread = (t, e)
  int t = tid >> 4, e = tid & 15;
  float s = b2[e];
  for (int j = 0; j < DH; ++j) s = fmaf(hs[t][j], w2s[j * NE + e], s);
  s *= TEMP_INV;
  float m = s;
#pragma unroll
  for (int d = 1; d < 16; d <<= 1) m = fmaxf(m, __shfl_xor(m, d));
  float p = expf(s - m);
  float sum = p;
#pragma unroll
  for (int d = 1; d < 16; d <<= 1) sum += __shfl_xor(sum, d);
  float prob = p / sum;
  out[OUT_PROBS + (size_t)(tok0 + t) * NE + e] = prob;
  ps[t][e] = prob;

  // usage partial (sum over wave's 4 tokens, then one atomic per e per wave)
  float v = prob;
  v += __shfl_xor(v, 16);
  v += __shfl_xor(v, 32);
  if ((tid & 63) < 16) atomicAdd(&usage[e], v);
  __syncthreads();

  // top-2 per token (stable: strict > keeps lowest index, matches lax.top_k)
  if (tid < 16) {
    int tt = tid;
    float v1 = -1.f; int i1 = 0;
    for (int ee = 0; ee < NE; ++ee) { float pv = ps[tt][ee]; if (pv > v1) { v1 = pv; i1 = ee; } }
    float v2 = -1.f; int i2 = 0;
    for (int ee = 0; ee < NE; ++ee) { if (ee == i1) continue; float pv = ps[tt][ee]; if (pv > v2) { v2 = pv; i2 = ee; } }
    float mm = fmaxf(v1, v2);
    float e0 = expf(v1 - mm), e1 = expf(v2 - mm);
    float rs = 1.f / (e0 + e1);
    int gt = tok0 + tt;
    wts[2 * gt]     = e0 * rs;
    wts[2 * gt + 1] = e1 * rs;
    int p1 = atomicAdd(&cnt[i1], 1);
    lists[i1 * CAP + p1] = 2 * gt;
    int p2 = atomicAdd(&cnt[i2], 1);
    lists[i2 * CAP + p2] = 2 * gt + 1;
  }
}

// ---------------- sched: tile descriptors + load-balance loss ----------------
__global__ void sched_kernel(const int* __restrict__ cnt,
                             const float* __restrict__ usage,
                             int* __restrict__ ntiles,
                             int2* __restrict__ desc,
                             float* __restrict__ out_loss) {
  if (threadIdx.x == 0) {
    int n = 0;
    for (int e = 0; e < NE; ++e) {
      int c = cnt[e];
      for (int i = 0; i < c; i += 128) { desc[n] = make_int2(e, i); ++n; }
    }
    *ntiles = n;
    float loss = 0.f;
    for (int e = 0; e < NE; ++e) {
      float d = usage[e] * (1.f / 4096.f) - (1.f / 16.f);
      loss += d * d;
    }
    *out_loss = loss * (1.f / 16.f);
  }
}

// ---------------- up GEMM: gather(x) @ up_w -> gelu -> hid (bf16) ----------------
__launch_bounds__(256)
__global__ void up_kernel(const float* __restrict__ x,
                          const float* __restrict__ up_w,
                          const float* __restrict__ up_b,
                          const int* __restrict__ cnt,
                          const int* __restrict__ ntiles,
                          const int2* __restrict__ desc,
                          const int* __restrict__ lists,
                          unsigned short* __restrict__ hid) {
  int ty = blockIdx.y;
  if (ty >= *ntiles) return;
  int2 dd = desc[ty];
  int e = dd.x, i0 = dd.y;
  int cntE = cnt[e];
  int f0 = blockIdx.x * 128;
  const float* __restrict__ W = up_w + (size_t)e * (DIM * FF);

  __shared__ __align__(16) unsigned short As[128 * 64];
  __shared__ __align__(16) unsigned short Bs[128 * 64];

  int tid = threadIdx.x;
  int ar = tid >> 1, ah = tid & 1;        // A staging: row, k-half
  int aidx = i0 + ar;
  int aslot = (aidx < cntE) ? lists[e * CAP + aidx] : 0;
  const float* __restrict__ xrow = x + (size_t)(aslot >> 1) * DIM;

  int kk8 = tid >> 5;                     // B staging: k-granule 0..7
  int n4 = (tid & 31) << 2;               // n base 0..124

  int lane = tid & 63, wid = tid >> 6;
  int wr = wid >> 1, wc = wid & 1;
  int ln15 = lane & 15, lq = lane >> 4;

  f32x4 acc[4][4];
#pragma unroll
  for (int i = 0; i < 4; ++i)
#pragma unroll
    for (int j = 0; j < 4; ++j) acc[i][j] = f32x4{0.f, 0.f, 0.f, 0.f};

  for (int ks = 0; ks < DIM / 64; ++ks) {
    int k0 = ks * 64;
    // A: fp32 gather -> bf16, XOR-swizzled 16B granules
#pragma unroll
    for (int i = 0; i < 4; ++i) {
      int g = (ah << 2) + i;
      float4 u = *(const float4*)(xrow + k0 + g * 8);
      float4 w = *(const float4*)(xrow + k0 + g * 8 + 4);
      u16x8 pk;
      pk[0] = f2bf(u.x); pk[1] = f2bf(u.y); pk[2] = f2bf(u.z); pk[3] = f2bf(u.w);
      pk[4] = f2bf(w.x); pk[5] = f2bf(w.y); pk[6] = f2bf(w.z); pk[7] = f2bf(w.w);
      *(u16x8*)(As + ar * 64 + ((g ^ (ar & 7)) << 3)) = pk;
    }
    // B: fp32 [k][n] -> bf16 Bt[n][k] (in-register 8x4 transpose)
    float4 bw[8];
#pragma unroll
    for (int rr = 0; rr < 8; ++rr)
      bw[rr] = *(const float4*)(W + (size_t)(k0 + kk8 * 8 + rr) * FF + f0 + n4);
#pragma unroll
    for (int c = 0; c < 4; ++c) {
      int n = n4 + c;
      u16x8 pk;
#pragma unroll
      for (int rr = 0; rr < 8; ++rr) pk[rr] = f2bf(gc(bw[rr], c));
      *(u16x8*)(Bs + n * 64 + ((kk8 ^ (n & 7)) << 3)) = pk;
    }
    __syncthreads();
#pragma unroll
    for (int ksub = 0; ksub < 2; ++ksub) {
      bf16x8 a[4], b[4];
      int g = (ksub << 2) + lq;
#pragma unroll
      for (int mi = 0; mi < 4; ++mi) {
        int arow = (wr << 6) + (mi << 4) + ln15;
        a[mi] = *(const bf16x8*)(As + arow * 64 + ((g ^ (arow & 7)) << 3));
      }
#pragma unroll
      for (int ni = 0; ni < 4; ++ni) {
        int bcol = (wc << 6) + (ni << 4) + ln15;
        b[ni] = *(const bf16x8*)(Bs + bcol * 64 + ((g ^ (bcol & 7)) << 3));
      }
#pragma unroll
      for (int mi = 0; mi < 4; ++mi)
#pragma unroll
        for (int ni = 0; ni < 4; ++ni)
          acc[mi][ni] = __builtin_amdgcn_mfma_f32_16x16x32_bf16(a[mi], b[ni], acc[mi][ni], 0, 0, 0);
    }
    __syncthreads();
  }
  // epilogue: bias + exact gelu -> hid bf16
#pragma unroll
  for (int mi = 0; mi < 4; ++mi) {
    int row_l = (wr << 6) + (mi << 4) + (lq << 2);
#pragma unroll
    for (int ni = 0; ni < 4; ++ni) {
      int col = (wc << 6) + (ni << 4) + ln15;
      float bias = up_b[e * FF + f0 + col];
#pragma unroll
      for (int q = 0; q < 4; ++q) {
        float vv = acc[mi][ni][q] + bias;
        float g = 0.5f * vv * (1.f + erff(vv * 0.70710678118f));
        hid[((size_t)ty * 128 + row_l + q) * FF + f0 + col] = f2bf(g);
      }
    }
  }
}

// ---------------- down GEMM: hid @ down_w -> per-pair-slot buffer ----------------
__launch_bounds__(256)
__global__ void down_kernel(const unsigned short* __restrict__ hid,
                            const float* __restrict__ down_w,
                            const float* __restrict__ down_b,
                            const int* __restrict__ cnt,
                            const int* __restrict__ ntiles,
                            const int2* __restrict__ desc,
                            const int* __restrict__ lists,
                            float* __restrict__ pairbuf) {
  int ty = blockIdx.y;
  if (ty >= *ntiles) return;
  int2 dd = desc[ty];
  int e = dd.x, i0 = dd.y;
  int cntE = cnt[e];
  int n0 = blockIdx.x * 128;
  const float* __restrict__ W = down_w + (size_t)e * (FF * DIM);

  __shared__ __align__(16) unsigned short As[128 * 64];
  __shared__ __align__(16) unsigned short Bs[128 * 64];

  int tid = threadIdx.x;
  int ar = tid >> 1, ah = tid & 1;
  const unsigned short* __restrict__ hrow = hid + ((size_t)ty * 128 + ar) * FF;

  int kk8 = tid >> 5;
  int n4 = (tid & 31) << 2;

  int lane = tid & 63, wid = tid >> 6;
  int wr = wid >> 1, wc = wid & 1;
  int ln15 = lane & 15, lq = lane >> 4;

  f32x4 acc[4][4];
#pragma unroll
  for (int i = 0; i < 4; ++i)
#pragma unroll
    for (int j = 0; j < 4; ++j) acc[i][j] = f32x4{0.f, 0.f, 0.f, 0.f};

  for (int ks = 0; ks < FF / 64; ++ks) {
    int k0 = ks * 64;
    // A: hid already bf16 -> direct 16B copy with swizzle
#pragma unroll
    for (int i = 0; i < 4; ++i) {
      int g = (ah << 2) + i;
      u16x8 pk = *(const u16x8*)(hrow + k0 + g * 8);
      *(u16x8*)(As + ar * 64 + ((g ^ (ar & 7)) << 3)) = pk;
    }
    // B: down_w fp32 [k][n] -> bf16 Bt[n][k]
    float4 bw[8];
#pragma unroll
    for (int rr = 0; rr < 8; ++rr)
      bw[rr] = *(const float4*)(W + (size_t)(k0 + kk8 * 8 + rr) * DIM + n0 + n4);
#pragma unroll
    for (int c = 0; c < 4; ++c) {
      int n = n4 + c;
      u16x8 pk;
#pragma unroll
      for (int rr = 0; rr < 8; ++rr) pk[rr] = f2bf(gc(bw[rr], c));
      *(u16x8*)(Bs + n * 64 + ((kk8 ^ (n & 7)) << 3)) = pk;
    }
    __syncthreads();
#pragma unroll
    for (int ksub = 0; ksub < 2; ++ksub) {
      bf16x8 a[4], b[4];
      int g = (ksub << 2) + lq;
#pragma unroll
      for (int mi = 0; mi < 4; ++mi) {
        int arow = (wr << 6) + (mi << 4) + ln15;
        a[mi] = *(const bf16x8*)(As + arow * 64 + ((g ^ (arow & 7)) << 3));
      }
#pragma unroll
      for (int ni = 0; ni < 4; ++ni) {
        int bcol = (wc << 6) + (ni << 4) + ln15;
        b[ni] = *(const bf16x8*)(Bs + bcol * 64 + ((g ^ (bcol & 7)) << 3));
      }
#pragma unroll
      for (int mi = 0; mi < 4; ++mi)
#pragma unroll
        for (int ni = 0; ni < 4; ++ni)
          acc[mi][ni] = __builtin_amdgcn_mfma_f32_16x16x32_bf16(a[mi], b[ni], acc[mi][ni], 0, 0, 0);
    }
    __syncthreads();
  }
  // epilogue: bias + scatter to pair slot (skip padded rows)
#pragma unroll
  for (int mi = 0; mi < 4; ++mi) {
    int row_l = (wr << 6) + (mi << 4) + (lq << 2);
#pragma unroll
    for (int ni = 0; ni < 4; ++ni) {
      int col = n0 + (wc << 6) + (ni << 4) + ln15;
      float bias = down_b[e * DIM + col];
#pragma unroll
      for (int q = 0; q < 4; ++q) {
        int idx = i0 + row_l + q;
        if (idx < cntE) {
          int slot = lists[e * CAP + idx];
          pairbuf[(size_t)slot * DIM + col] = acc[mi][ni][q] + bias;
        }
      }
    }
  }
}

// ---------------- combine: out[t] = w0*pair[2t] + w1*pair[2t+1] ----------------
__launch_bounds__(256)
__global__ void combine_kernel(const float* __restrict__ pairbuf,
                               const float* __restrict__ wts,
                               float* __restrict__ out) {
  int t = blockIdx.x;
  int d = threadIdx.x << 1;
  float w0 = wts[2 * t], w1 = wts[2 * t + 1];
  float2 a = *(const float2*)(pairbuf + (size_t)(2 * t) * DIM + d);
  float2 b = *(const float2*)(pairbuf + (size_t)(2 * t + 1) * DIM + d);
  float2 r; r.x = w0 * a.x + w1 * b.x; r.y = w0 * a.y + w1 * b.y;
  *(float2*)(out + (size_t)t * DIM + d) = r;
}

extern "C" void kernel_launch(void* const* d_in, const int* in_sizes, int n_in,
                              void* d_out, int out_size, void* d_ws, size_t ws_size,
                              hipStream_t stream) {
  (void)in_sizes; (void)n_in; (void)out_size; (void)ws_size;
  const float* x   = (const float*)d_in[0];
  const float* gw1 = (const float*)d_in[1];
  const float* gb1 = (const float*)d_in[2];
  const float* gw2 = (const float*)d_in[3];
  const float* gb2 = (const float*)d_in[4];
  const float* uw  = (const float*)d_in[5];
  const float* ub  = (const float*)d_in[6];
  const float* dw  = (const float*)d_in[7];
  const float* db  = (const float*)d_in[8];
  float* out = (float*)d_out;
  char* ws = (char*)d_ws;

  int*   cnt     = (int*)(ws + WS_CNT);
  float* usage   = (float*)(ws + WS_USAGE);
  int*   ntiles  = (int*)(ws + WS_NTILES);
  int2*  desc    = (int2*)(ws + WS_DESC);
  float* wts     = (float*)(ws + WS_WTS);
  int*   lists   = (int*)(ws + WS_LISTS);
  unsigned short* hid = (unsigned short*)(ws + WS_HID);
  float* pairbuf = (float*)(ws + WS_PAIR);

  hipMemsetAsync(d_ws, 0, 1024, stream);  // zero cnt/usage/ntiles/desc
  router_kernel<<<NTOK / 16, 256, 0, stream>>>(x, gw1, gb1, gw2, gb2, out, cnt, usage, wts, lists);
  sched_kernel<<<1, 64, 0, stream>>>(cnt, usage, ntiles, desc, out + OUT_LOSS);
  up_kernel<<<dim3(FF / 128, MAXTILES), 256, 0, stream>>>(x, uw, ub, cnt, ntiles, desc, lists, hid);
  down_kernel<<<dim3(DIM / 128, MAXTILES), 256, 0, stream>>>(hid, dw, db, cnt, ntiles, desc, lists, pairbuf);
  combine_kernel<<<NTOK, 256, 0, stream>>>(pairbuf, wts, out);
}

// Round 2
// 415.293 us; speedup vs baseline: 1.0288x; 1.0288x over previous
//
#include <hip/hip_runtime.h>
#include <hip/hip_bf16.h>

// Problem constants
#define NTOK 4096      // B*S
#define DIM  512       // D
#define DH   256       // D/2
#define NE   16        // experts
#define FF   2048      // F
#define CAP  8192      // per-expert list capacity
#define MAXTILES 80    // sum ceil(cnt_e/128) <= 79
#define TEMP_INV 2.0f  // 1/temperature
#define RTOK 8         // tokens per router block

// out layout: [NTOK*DIM output][1 loss][NTOK*NE probs]
#define OUT_LOSS  (NTOK * DIM)
#define OUT_PROBS (NTOK * DIM + 1)

// ws layout (bytes)
#define WS_CNT    0            // int[16]
#define WS_USAGE  64           // float[16]
#define WS_NTILES 128          // int
#define WS_DESC   256          // int2[80]
#define WS_WTS    1024         // float[2*NTOK]
#define WS_LISTS  36864        // int[16*CAP]
#define WS_HID    (1u << 20)   // bf16 [80*128][FF]  (~40MB)
#define WS_PAIR   (48u << 20)  // float [2*NTOK][DIM] (16MB)

typedef __attribute__((ext_vector_type(8))) short bf16x8;           // MFMA A/B frag
typedef __attribute__((ext_vector_type(8))) unsigned short u16x8;   // 8 bf16 storage
typedef __attribute__((ext_vector_type(4))) float f32x4;            // MFMA C/D frag

__device__ __forceinline__ unsigned short f2bf(float f) {  // RNE f32->bf16
  union { float f; unsigned u; } c; c.f = f;
  return (unsigned short)((c.u + 0x7FFFu + ((c.u >> 16) & 1u)) >> 16);
}
__device__ __forceinline__ float gc(const float4& v, int c) {
  return c == 0 ? v.x : c == 1 ? v.y : c == 2 ? v.z : v.w;
}

// ---------------- router: fp32 gate MLP + softmax + top2 + lists ----------------
// v2: 8 tokens/block (512 blocks -> 2 blocks/CU, 2 waves/SIMD) + 4-deep w1
// register prefetch so L2 latency (~250cy) hides under 4x64cy of FMA.
__launch_bounds__(256)
__global__ void router_kernel(const float* __restrict__ x,
                              const float* __restrict__ w1,
                              const float* __restrict__ b1,
                              const float* __restrict__ w2,
                              const float* __restrict__ b2,
                              float* __restrict__ out,
                              int* __restrict__ cnt,
                              float* __restrict__ usage,
                              float* __restrict__ wts,
                              int* __restrict__ lists) {
  __shared__ __align__(16) float xs[RTOK][DIM];     // 16KB
  __shared__ __align__(16) float hs[RTOK][DH + 4];  // 8.3KB padded
  __shared__ __align__(16) float w2s[DH * NE];      // 16KB
  __shared__ float ps[RTOK][NE];
  __shared__ float us[2][NE];

  int tid = threadIdx.x;
  int tok0 = blockIdx.x * RTOK;

  // stage x tile + w2
  {
    const float4* xg = (const float4*)(x + (size_t)tok0 * DIM);
    float4* xv = (float4*)&xs[0][0];
    for (int i = tid; i < RTOK * DIM / 4; i += 256) xv[i] = xg[i];
    for (int i = tid; i < DH * NE; i += 256) w2s[i] = w2[i];
  }
  __syncthreads();

  // h = relu(x @ w1 + b1): thread j computes column j for RTOK tokens.
  // w1 loads pipelined 4 groups (16 k) deep in rotating registers.
  {
    int j = tid;
    float acc[RTOK];
    float bj = b1[j];
#pragma unroll
    for (int t = 0; t < RTOK; ++t) acc[t] = bj;

    float wq[4][4];
#pragma unroll
    for (int g = 0; g < 4; ++g)
#pragma unroll
      for (int u = 0; u < 4; ++u)
        wq[g][u] = w1[(size_t)(g * 4 + u) * DH + j];

#pragma unroll 4
    for (int g = 0; g < DIM / 4; ++g) {
      float wcur[4];
#pragma unroll
      for (int u = 0; u < 4; ++u) wcur[u] = wq[g & 3][u];
      int gn = g + 4;
      if (gn < DIM / 4) {
#pragma unroll
        for (int u = 0; u < 4; ++u) wq[g & 3][u] = w1[(size_t)(gn * 4 + u) * DH + j];
      }
      int k = g * 4;
#pragma unroll
      for (int t = 0; t < RTOK; ++t) {
        float4 xq = *(const float4*)&xs[t][k];
        acc[t] = fmaf(xq.x, wcur[0], acc[t]);
        acc[t] = fmaf(xq.y, wcur[1], acc[t]);
        acc[t] = fmaf(xq.z, wcur[2], acc[t]);
        acc[t] = fmaf(xq.w, wcur[3], acc[t]);
      }
    }
#pragma unroll
    for (int t = 0; t < RTOK; ++t) hs[t][j] = fmaxf(acc[t], 0.f);
  }
  __syncthreads();

  // scores + softmax: thread = (t, e) for t<8 (waves 0,1)
  int t = tid >> 4, e = tid & 15;
  if (tid < 128) {
    float s = b2[e];
#pragma unroll 8
    for (int jj = 0; jj < DH; ++jj) s = fmaf(hs[t][jj], w2s[jj * NE + e], s);
    s *= TEMP_INV;
    float m = s;
#pragma unroll
    for (int d = 1; d < 16; d <<= 1) m = fmaxf(m, __shfl_xor(m, d));
    float p = expf(s - m);
    float sum = p;
#pragma unroll
    for (int d = 1; d < 16; d <<= 1) sum += __shfl_xor(sum, d);
    float prob = p / sum;
    out[OUT_PROBS + (size_t)(tok0 + t) * NE + e] = prob;
    ps[t][e] = prob;

    // usage partial: sum over this wave's 4 tokens -> LDS, combined below
    float v = prob;
    v += __shfl_xor(v, 16);
    v += __shfl_xor(v, 32);
    if ((tid & 63) < 16) us[tid >> 6][e] = v;
  }
  __syncthreads();
  if (tid < 16) atomicAdd(&usage[tid], us[0][tid] + us[1][tid]);

  // top-2 per token (stable: strict > keeps lowest index, matches lax.top_k)
  if (tid < RTOK) {
    int tt = tid;
    float v1 = -1.f; int i1 = 0;
    for (int ee = 0; ee < NE; ++ee) { float pv = ps[tt][ee]; if (pv > v1) { v1 = pv; i1 = ee; } }
    float v2 = -1.f; int i2 = 0;
    for (int ee = 0; ee < NE; ++ee) { if (ee == i1) continue; float pv = ps[tt][ee]; if (pv > v2) { v2 = pv; i2 = ee; } }
    float mm = fmaxf(v1, v2);
    float e0 = expf(v1 - mm), e1 = expf(v2 - mm);
    float rs = 1.f / (e0 + e1);
    int gt = tok0 + tt;
    wts[2 * gt]     = e0 * rs;
    wts[2 * gt + 1] = e1 * rs;
    int p1 = atomicAdd(&cnt[i1], 1);
    lists[i1 * CAP + p1] = 2 * gt;
    int p2 = atomicAdd(&cnt[i2], 1);
    lists[i2 * CAP + p2] = 2 * gt + 1;
  }
}

// ---------------- sched: one wave; shfl scan for descs + loss ----------------
__global__ void sched_kernel(const int* __restrict__ cnt,
                             const float* __restrict__ usage,
                             int* __restrict__ ntiles,
                             int2* __restrict__ desc,
                             float* __restrict__ out_loss) {
  int lane = threadIdx.x;          // 64 threads, lanes 0..15 active
  int e = lane & 15;
  int c = (lane < 16) ? cnt[e] : 0;
  int tl = (c + 127) >> 7;
  int v = tl;
#pragma unroll
  for (int d = 1; d < 16; d <<= 1) {
    int u = __shfl_up(v, d);
    if (lane >= d) v += u;
  }
  int excl = v - tl;
  int tot = __shfl(v, 15);
  if (lane == 0) *ntiles = tot;
  if (lane < 16) {
    for (int i = 0; i < tl; ++i) desc[excl + i] = make_int2(e, i << 7);
    float d0 = usage[e] * (1.f / 4096.f) - (1.f / 16.f);
    float ls = d0 * d0;
#pragma unroll
    for (int d = 1; d < 16; d <<= 1) ls += __shfl_xor(ls, d);
    if (lane == 0) *out_loss = ls * (1.f / 16.f);
  }
}

// ---------------- up GEMM: gather(x) @ up_w -> gelu -> hid (bf16) ----------------
__launch_bounds__(256)
__global__ void up_kernel(const float* __restrict__ x,
                          const float* __restrict__ up_w,
                          const float* __restrict__ up_b,
                          const int* __restrict__ cnt,
                          const int* __restrict__ ntiles,
                          const int2* __restrict__ desc,
                          const int* __restrict__ lists,
                          unsigned short* __restrict__ hid) {
  int ty = blockIdx.y;
  if (ty >= *ntiles) return;
  int2 dd = desc[ty];
  int e = dd.x, i0 = dd.y;
  int cntE = cnt[e];
  int f0 = blockIdx.x * 128;
  const float* __restrict__ W = up_w + (size_t)e * (DIM * FF);

  __shared__ __align__(16) unsigned short As[128 * 64];
  __shared__ __align__(16) unsigned short Bs[128 * 64];

  int tid = threadIdx.x;
  int ar = tid >> 1, ah = tid & 1;        // A staging: row, k-half
  int aidx = i0 + ar;
  int aslot = (aidx < cntE) ? lists[e * CAP + aidx] : 0;
  const float* __restrict__ xrow = x + (size_t)(aslot >> 1) * DIM;

  int kk8 = tid >> 5;                     // B staging: k-granule 0..7
  int n4 = (tid & 31) << 2;               // n base 0..124

  int lane = tid & 63, wid = tid >> 6;
  int wr = wid >> 1, wc = wid & 1;
  int ln15 = lane & 15, lq = lane >> 4;

  f32x4 acc[4][4];
#pragma unroll
  for (int i = 0; i < 4; ++i)
#pragma unroll
    for (int j = 0; j < 4; ++j) acc[i][j] = f32x4{0.f, 0.f, 0.f, 0.f};

  for (int ks = 0; ks < DIM / 64; ++ks) {
    int k0 = ks * 64;
    // A: fp32 gather -> bf16, XOR-swizzled 16B granules
#pragma unroll
    for (int i = 0; i < 4; ++i) {
      int g = (ah << 2) + i;
      float4 u = *(const float4*)(xrow + k0 + g * 8);
      float4 w = *(const float4*)(xrow + k0 + g * 8 + 4);
      u16x8 pk;
      pk[0] = f2bf(u.x); pk[1] = f2bf(u.y); pk[2] = f2bf(u.z); pk[3] = f2bf(u.w);
      pk[4] = f2bf(w.x); pk[5] = f2bf(w.y); pk[6] = f2bf(w.z); pk[7] = f2bf(w.w);
      *(u16x8*)(As + ar * 64 + ((g ^ (ar & 7)) << 3)) = pk;
    }
    // B: fp32 [k][n] -> bf16 Bt[n][k] (in-register 8x4 transpose)
    float4 bw[8];
#pragma unroll
    for (int rr = 0; rr < 8; ++rr)
      bw[rr] = *(const float4*)(W + (size_t)(k0 + kk8 * 8 + rr) * FF + f0 + n4);
#pragma unroll
    for (int c = 0; c < 4; ++c) {
      int n = n4 + c;
      u16x8 pk;
#pragma unroll
      for (int rr = 0; rr < 8; ++rr) pk[rr] = f2bf(gc(bw[rr], c));
      *(u16x8*)(Bs + n * 64 + ((kk8 ^ (n & 7)) << 3)) = pk;
    }
    __syncthreads();
#pragma unroll
    for (int ksub = 0; ksub < 2; ++ksub) {
      bf16x8 a[4], b[4];
      int g = (ksub << 2) + lq;
#pragma unroll
      for (int mi = 0; mi < 4; ++mi) {
        int arow = (wr << 6) + (mi << 4) + ln15;
        a[mi] = *(const bf16x8*)(As + arow * 64 + ((g ^ (arow & 7)) << 3));
      }
#pragma unroll
      for (int ni = 0; ni < 4; ++ni) {
        int bcol = (wc << 6) + (ni << 4) + ln15;
        b[ni] = *(const bf16x8*)(Bs + bcol * 64 + ((g ^ (bcol & 7)) << 3));
      }
#pragma unroll
      for (int mi = 0; mi < 4; ++mi)
#pragma unroll
        for (int ni = 0; ni < 4; ++ni)
          acc[mi][ni] = __builtin_amdgcn_mfma_f32_16x16x32_bf16(a[mi], b[ni], acc[mi][ni], 0, 0, 0);
    }
    __syncthreads();
  }
  // epilogue: bias + exact gelu -> hid bf16
#pragma unroll
  for (int mi = 0; mi < 4; ++mi) {
    int row_l = (wr << 6) + (mi << 4) + (lq << 2);
#pragma unroll
    for (int ni = 0; ni < 4; ++ni) {
      int col = (wc << 6) + (ni << 4) + ln15;
      float bias = up_b[e * FF + f0 + col];
#pragma unroll
      for (int q = 0; q < 4; ++q) {
        float vv = acc[mi][ni][q] + bias;
        float g = 0.5f * vv * (1.f + erff(vv * 0.70710678118f));
        hid[((size_t)ty * 128 + row_l + q) * FF + f0 + col] = f2bf(g);
      }
    }
  }
}

// ---------------- down GEMM: hid @ down_w -> per-pair-slot buffer ----------------
__launch_bounds__(256)
__global__ void down_kernel(const unsigned short* __restrict__ hid,
                            const float* __restrict__ down_w,
                            const float* __restrict__ down_b,
                            const int* __restrict__ cnt,
                            const int* __restrict__ ntiles,
                            const int2* __restrict__ desc,
                            const int* __restrict__ lists,
                            float* __restrict__ pairbuf) {
  int ty = blockIdx.y;
  if (ty >= *ntiles) return;
  int2 dd = desc[ty];
  int e = dd.x, i0 = dd.y;
  int cntE = cnt[e];
  int n0 = blockIdx.x * 128;
  const float* __restrict__ W = down_w + (size_t)e * (FF * DIM);

  __shared__ __align__(16) unsigned short As[128 * 64];
  __shared__ __align__(16) unsigned short Bs[128 * 64];

  int tid = threadIdx.x;
  int ar = tid >> 1, ah = tid & 1;
  const unsigned short* __restrict__ hrow = hid + ((size_t)ty * 128 + ar) * FF;

  int kk8 = tid >> 5;
  int n4 = (tid & 31) << 2;

  int lane = tid & 63, wid = tid >> 6;
  int wr = wid >> 1, wc = wid & 1;
  int ln15 = lane & 15, lq = lane >> 4;

  f32x4 acc[4][4];
#pragma unroll
  for (int i = 0; i < 4; ++i)
#pragma unroll
    for (int j = 0; j < 4; ++j) acc[i][j] = f32x4{0.f, 0.f, 0.f, 0.f};

  for (int ks = 0; ks < FF / 64; ++ks) {
    int k0 = ks * 64;
    // A: hid already bf16 -> direct 16B copy with swizzle
#pragma unroll
    for (int i = 0; i < 4; ++i) {
      int g = (ah << 2) + i;
      u16x8 pk = *(const u16x8*)(hrow + k0 + g * 8);
      *(u16x8*)(As + ar * 64 + ((g ^ (ar & 7)) << 3)) = pk;
    }
    // B: down_w fp32 [k][n] -> bf16 Bt[n][k]
    float4 bw[8];
#pragma unroll
    for (int rr = 0; rr < 8; ++rr)
      bw[rr] = *(const float4*)(W + (size_t)(k0 + kk8 * 8 + rr) * DIM + n0 + n4);
#pragma unroll
    for (int c = 0; c < 4; ++c) {
      int n = n4 + c;
      u16x8 pk;
#pragma unroll
      for (int rr = 0; rr < 8; ++rr) pk[rr] = f2bf(gc(bw[rr], c));
      *(u16x8*)(Bs + n * 64 + ((kk8 ^ (n & 7)) << 3)) = pk;
    }
    __syncthreads();
#pragma unroll
    for (int ksub = 0; ksub < 2; ++ksub) {
      bf16x8 a[4], b[4];
      int g = (ksub << 2) + lq;
#pragma unroll
      for (int mi = 0; mi < 4; ++mi) {
        int arow = (wr << 6) + (mi << 4) + ln15;
        a[mi] = *(const bf16x8*)(As + arow * 64 + ((g ^ (arow & 7)) << 3));
      }
#pragma unroll
      for (int ni = 0; ni < 4; ++ni) {
        int bcol = (wc << 6) + (ni << 4) + ln15;
        b[ni] = *(const bf16x8*)(Bs + bcol * 64 + ((g ^ (bcol & 7)) << 3));
      }
#pragma unroll
      for (int mi = 0; mi < 4; ++mi)
#pragma unroll
        for (int ni = 0; ni < 4; ++ni)
          acc[mi][ni] = __builtin_amdgcn_mfma_f32_16x16x32_bf16(a[mi], b[ni], acc[mi][ni], 0, 0, 0);
    }
    __syncthreads();
  }
  // epilogue: bias + scatter to pair slot (skip padded rows)
#pragma unroll
  for (int mi = 0; mi < 4; ++mi) {
    int row_l = (wr << 6) + (mi << 4) + (lq << 2);
#pragma unroll
    for (int ni = 0; ni < 4; ++ni) {
      int col = n0 + (wc << 6) + (ni << 4) + ln15;
      float bias = down_b[e * DIM + col];
#pragma unroll
      for (int q = 0; q < 4; ++q) {
        int idx = i0 + row_l + q;
        if (idx < cntE) {
          int slot = lists[e * CAP + idx];
          pairbuf[(size_t)slot * DIM + col] = acc[mi][ni][q] + bias;
        }
      }
    }
  }
}

// ---------------- combine: out[t] = w0*pair[2t] + w1*pair[2t+1] ----------------
__launch_bounds__(256)
__global__ void combine_kernel(const float* __restrict__ pairbuf,
                               const float* __restrict__ wts,
                               float* __restrict__ out) {
  int t = blockIdx.x;
  int d = threadIdx.x << 1;
  float w0 = wts[2 * t], w1 = wts[2 * t + 1];
  float2 a = *(const float2*)(pairbuf + (size_t)(2 * t) * DIM + d);
  float2 b = *(const float2*)(pairbuf + (size_t)(2 * t + 1) * DIM + d);
  float2 r; r.x = w0 * a.x + w1 * b.x; r.y = w0 * a.y + w1 * b.y;
  *(float2*)(out + (size_t)t * DIM + d) = r;
}

extern "C" void kernel_launch(void* const* d_in, const int* in_sizes, int n_in,
                              void* d_out, int out_size, void* d_ws, size_t ws_size,
                              hipStream_t stream) {
  (void)in_sizes; (void)n_in; (void)out_size; (void)ws_size;
  const float* x   = (const float*)d_in[0];
  const float* gw1 = (const float*)d_in[1];
  const float* gb1 = (const float*)d_in[2];
  const float* gw2 = (const float*)d_in[3];
  const float* gb2 = (const float*)d_in[4];
  const float* uw  = (const float*)d_in[5];
  const float* ub  = (const float*)d_in[6];
  const float* dw  = (const float*)d_in[7];
  const float* db  = (const float*)d_in[8];
  float* out = (float*)d_out;
  char* ws = (char*)d_ws;

  int*   cnt     = (int*)(ws + WS_CNT);
  float* usage   = (float*)(ws + WS_USAGE);
  int*   ntiles  = (int*)(ws + WS_NTILES);
  int2*  desc    = (int2*)(ws + WS_DESC);
  float* wts     = (float*)(ws + WS_WTS);
  int*   lists   = (int*)(ws + WS_LISTS);
  unsigned short* hid = (unsigned short*)(ws + WS_HID);
  float* pairbuf = (float*)(ws + WS_PAIR);

  hipMemsetAsync(d_ws, 0, 1024, stream);  // zero cnt/usage/ntiles/desc
  router_kernel<<<NTOK / RTOK, 256, 0, stream>>>(x, gw1, gb1, gw2, gb2, out, cnt, usage, wts, lists);
  sched_kernel<<<1, 64, 0, stream>>>(cnt, usage, ntiles, desc, out + OUT_LOSS);
  up_kernel<<<dim3(FF / 128, MAXTILES), 256, 0, stream>>>(x, uw, ub, cnt, ntiles, desc, lists, hid);
  down_kernel<<<dim3(DIM / 128, MAXTILES), 256, 0, stream>>>(hid, dw, db, cnt, ntiles, desc, lists, pairbuf);
  combine_kernel<<<NTOK, 256, 0, stream>>>(pairbuf, wts, out);
}

// Round 3
// 378.957 us; speedup vs baseline: 1.1275x; 1.0959x over previous
//
#include <hip/hip_runtime.h>
#include <hip/hip_bf16.h>

// Problem constants
#define NTOK 4096      // B*S
#define DIM  512       // D
#define DH   256       // D/2
#define NE   16        // experts
#define FF   2048      // F
#define CAP  8192      // per-expert list capacity
#define MAXTILES 80    // sum ceil(cnt_e/128) <= 79
#define TEMP_INV 2.0f  // 1/temperature

// out layout: [NTOK*DIM output][1 loss][NTOK*NE probs]
#define OUT_LOSS  (NTOK * DIM)
#define OUT_PROBS (NTOK * DIM + 1)

// ws layout (bytes). Temporal reuse:
//   H (4MB, dead after score) and G (10MB, written after) share [1MB..).
//   pairbuf (16MB, written by down) reuses T_up region (dead after up).
#define WS_CNT    0            // int[16]
#define WS_USAGE  64           // float[16]
#define WS_NTILES 128          // int
#define WS_DESC   256          // int2[80]
#define WS_WTS    1024         // float[2*NTOK]
#define WS_LISTS  36864        // int[16*CAP] (512KB)
#define WS_H      (1ull<<20)   // fp32 [4096][256] = 4MB
#define WS_G      (1ull<<20)   // bf16 [80][8][128][64] = 10MB
#define WS_TUP    (16ull<<20)  // bf16 [16][8][2048][64] = 32MB
#define WS_PAIR   (16ull<<20)  // fp32 [8192][512] = 16MB (after T_up dead)
#define WS_TDN    (48ull<<20)  // bf16 [16][32][512][64] = 32MB
#define WS_HID    (80ull<<20)  // bf16 [80][32][128][64] = 40MB

typedef __attribute__((ext_vector_type(8))) short bf16x8;           // MFMA A/B frag
typedef __attribute__((ext_vector_type(8))) unsigned short u16x8;   // 8 bf16 storage
typedef __attribute__((ext_vector_type(4))) float f32x4;            // MFMA C/D frag

__device__ __forceinline__ unsigned short f2bf(float f) {  // RNE f32->bf16
  union { float f; unsigned u; } c; c.f = f;
  return (unsigned short)((c.u + 0x7FFFu + ((c.u >> 16) & 1u)) >> 16);
}

// async global->LDS, 16B per lane. LDS dest = wave-uniform base + lane*16.
#define GLOAD16(gp, lp) __builtin_amdgcn_global_load_lds( \
    (const __attribute__((address_space(1))) void*)(gp), \
    (__attribute__((address_space(3))) void*)(lp), 16, 0, 0)

// =================== fused0: router-h GEMM + weight transpose/convert ===================
// blocks [0,512): h = relu(x@w1+b1) -> H (fp32), 64tok x 32col tiles, 4x2/thread
// blocks [512,1536):  up_w  fp32 [e][512k][2048f] -> T_up  bf16 [e][kc8][2048f][64k]
// blocks [1536,2560): down_w fp32 [e][2048k][512d] -> T_dn bf16 [e][kc32][512d][64k]
__launch_bounds__(256)
__global__ void fused0_kernel(const float* __restrict__ x,
                              const float* __restrict__ w1,
                              const float* __restrict__ b1,
                              const float* __restrict__ up_w,
                              const float* __restrict__ down_w,
                              float* __restrict__ H,
                              unsigned short* __restrict__ Tup,
                              unsigned short* __restrict__ Tdn) {
  __shared__ __align__(16) char smem[33792];
  int bx = blockIdx.x, tid = threadIdx.x;

  if (bx < 512) {
    // ---- router h GEMM ----
    float* As = (float*)smem;               // [32k][68 tok-pad]
    float* Bs = (float*)(smem + 32 * 68 * 4); // [32k][36 col-pad]
    int mb = bx >> 3, nb = bx & 7;
    int tok0 = mb * 64, n0 = nb * 32;
    int ty = tid >> 4, tx = tid & 15;
    float acc[4][2];
#pragma unroll
    for (int i = 0; i < 4; ++i) { acc[i][0] = 0.f; acc[i][1] = 0.f; }

    for (int kc = 0; kc < 16; ++kc) {
      int k0 = kc * 32;
      // stage A: x[64tok][32k] -> As[k][tok]
      {
        int tk = tid >> 2, kg = (tid & 3) * 8;
        const float* xp = x + (size_t)(tok0 + tk) * DIM + k0 + kg;
        float4 v0 = *(const float4*)xp;
        float4 v1 = *(const float4*)(xp + 4);
        As[(kg + 0) * 68 + tk] = v0.x; As[(kg + 1) * 68 + tk] = v0.y;
        As[(kg + 2) * 68 + tk] = v0.z; As[(kg + 3) * 68 + tk] = v0.w;
        As[(kg + 4) * 68 + tk] = v1.x; As[(kg + 5) * 68 + tk] = v1.y;
        As[(kg + 6) * 68 + tk] = v1.z; As[(kg + 7) * 68 + tk] = v1.w;
      }
      // stage B: w1[32k][32n] (row-major [512][256]) -> Bs[k][n]
      {
        int k = tid >> 3, nn = (tid & 7) * 4;
        *(float4*)&Bs[k * 36 + nn] = *(const float4*)(w1 + (size_t)(k0 + k) * DH + n0 + nn);
      }
      __syncthreads();
#pragma unroll 8
      for (int k = 0; k < 32; ++k) {
        float4 a = *(const float4*)&As[k * 68 + ty * 4];
        float2 b = *(const float2*)&Bs[k * 36 + tx * 2];
#pragma unroll
        for (int i = 0; i < 4; ++i) {
          float av = (i == 0) ? a.x : (i == 1) ? a.y : (i == 2) ? a.z : a.w;
          acc[i][0] = fmaf(av, b.x, acc[i][0]);
          acc[i][1] = fmaf(av, b.y, acc[i][1]);
        }
      }
      __syncthreads();
    }
    float bj0 = b1[n0 + tx * 2], bj1 = b1[n0 + tx * 2 + 1];
#pragma unroll
    for (int i = 0; i < 4; ++i) {
      float2 st;
      st.x = fmaxf(acc[i][0] + bj0, 0.f);
      st.y = fmaxf(acc[i][1] + bj1, 0.f);
      *(float2*)(H + (size_t)(tok0 + ty * 4 + i) * DH + n0 + tx * 2) = st;
    }
  } else {
    // ---- weight transpose-convert: [64k][256n] fp32 tile -> [256n][64k] bf16 ----
    const float* src; unsigned short* dst; int srcStride;
    if (bx < 1536) {
      int u = bx - 512;                      // e(4b) kc(3b) fb(3b)
      int e = u >> 6, kc = (u >> 3) & 7, fb = u & 7;
      src = up_w + (size_t)e * DIM * FF + (size_t)kc * 64 * FF + fb * 256;
      srcStride = FF;
      dst = Tup + ((size_t)(e * 8 + kc) * FF + fb * 256) * 64;
    } else {
      int d = bx - 1536;                     // e(4b) kc(5b) nb(1b)
      int e = d >> 6, kc = (d >> 1) & 31, nb = d & 1;
      src = down_w + (size_t)e * FF * DIM + (size_t)kc * 64 * DIM + nb * 256;
      srcStride = DIM;
      dst = Tdn + ((size_t)(e * 32 + kc) * DIM + nb * 256) * 64;
    }
    unsigned short* L = (unsigned short*)smem;  // [64][264]
#pragma unroll
    for (int i = 0; i < 16; ++i) {
      int idx = tid + i * 256;                  // over [64 rows][64 float4]
      int row = idx >> 6, c4 = idx & 63;
      float4 v = *(const float4*)(src + (size_t)row * srcStride + c4 * 4);
      unsigned short* p = L + row * 264 + c4 * 4;
      p[0] = f2bf(v.x); p[1] = f2bf(v.y); p[2] = f2bf(v.z); p[3] = f2bf(v.w);
    }
    __syncthreads();
    // thread tid = output col n; gather 64 k values (transposed), write 128B row
#pragma unroll
    for (int j = 0; j < 8; ++j) {
      u16x8 pk;
#pragma unroll
      for (int k = 0; k < 8; ++k) pk[k] = L[(j * 8 + k) * 264 + tid];
      *(u16x8*)(dst + (size_t)tid * 64 + j * 8) = pk;
    }
  }
}

// =================== score: softmax + top2 + lists (per 16 tokens) ===================
__launch_bounds__(256)
__global__ void score_kernel(const float* __restrict__ H,
                             const float* __restrict__ w2,
                             const float* __restrict__ b2,
                             float* __restrict__ out,
                             int* __restrict__ cnt,
                             float* __restrict__ usage,
                             float* __restrict__ wts,
                             int* __restrict__ lists) {
  __shared__ __align__(16) float hs[16][260];
  __shared__ __align__(16) float w2t[16][260];
  __shared__ float ps[16][NE];
  __shared__ float us[4][NE];
  int tid = threadIdx.x;
  int tok0 = blockIdx.x * 16;
  {
    int r = tid >> 4, seg = tid & 15;
    const float* hp = H + (size_t)(tok0 + r) * DH + seg * 16;
    *(float4*)&hs[r][seg * 16 + 0]  = *(const float4*)(hp + 0);
    *(float4*)&hs[r][seg * 16 + 4]  = *(const float4*)(hp + 4);
    *(float4*)&hs[r][seg * 16 + 8]  = *(const float4*)(hp + 8);
    *(float4*)&hs[r][seg * 16 + 12] = *(const float4*)(hp + 12);
  }
  {
    // w2 [256][16] -> w2t[e][j]
    float4 a = *(const float4*)(w2 + (size_t)tid * 16 + 0);
    float4 b = *(const float4*)(w2 + (size_t)tid * 16 + 4);
    float4 c = *(const float4*)(w2 + (size_t)tid * 16 + 8);
    float4 d = *(const float4*)(w2 + (size_t)tid * 16 + 12);
    w2t[0][tid] = a.x;  w2t[1][tid] = a.y;  w2t[2][tid] = a.z;  w2t[3][tid] = a.w;
    w2t[4][tid] = b.x;  w2t[5][tid] = b.y;  w2t[6][tid] = b.z;  w2t[7][tid] = b.w;
    w2t[8][tid] = c.x;  w2t[9][tid] = c.y;  w2t[10][tid] = c.z; w2t[11][tid] = c.w;
    w2t[12][tid] = d.x; w2t[13][tid] = d.y; w2t[14][tid] = d.z; w2t[15][tid] = d.w;
  }
  __syncthreads();
  int t = tid >> 4, e = tid & 15;
  float s = b2[e];
#pragma unroll 4
  for (int j4 = 0; j4 < 64; ++j4) {
    float4 hv = *(const float4*)&hs[t][j4 * 4];
    float4 wv = *(const float4*)&w2t[e][j4 * 4];
    s = fmaf(hv.x, wv.x, fmaf(hv.y, wv.y, fmaf(hv.z, wv.z, fmaf(hv.w, wv.w, s))));
  }
  s *= TEMP_INV;
  float m = s;
#pragma unroll
  for (int d = 1; d < 16; d <<= 1) m = fmaxf(m, __shfl_xor(m, d));
  float p = expf(s - m);
  float sum = p;
#pragma unroll
  for (int d = 1; d < 16; d <<= 1) sum += __shfl_xor(sum, d);
  float prob = p / sum;
  out[OUT_PROBS + (size_t)(tok0 + t) * NE + e] = prob;
  ps[t][e] = prob;
  float v = prob;
  v += __shfl_xor(v, 16);
  v += __shfl_xor(v, 32);
  if ((tid & 63) < 16) us[tid >> 6][e] = v;
  __syncthreads();
  if (tid < 16) atomicAdd(&usage[tid], us[0][tid] + us[1][tid] + us[2][tid] + us[3][tid]);

  if (tid < 16) {
    int tt = tid;
    float v1 = -1.f; int i1 = 0;
    for (int ee = 0; ee < NE; ++ee) { float pv = ps[tt][ee]; if (pv > v1) { v1 = pv; i1 = ee; } }
    float v2 = -1.f; int i2 = 0;
    for (int ee = 0; ee < NE; ++ee) { if (ee == i1) continue; float pv = ps[tt][ee]; if (pv > v2) { v2 = pv; i2 = ee; } }
    float mm = fmaxf(v1, v2);
    float e0 = expf(v1 - mm), e1 = expf(v2 - mm);
    float rs = 1.f / (e0 + e1);
    int gt = tok0 + tt;
    wts[2 * gt]     = e0 * rs;
    wts[2 * gt + 1] = e1 * rs;
    int p1 = atomicAdd(&cnt[i1], 1);
    lists[i1 * CAP + p1] = 2 * gt;
    int p2 = atomicAdd(&cnt[i2], 1);
    lists[i2 * CAP + p2] = 2 * gt + 1;
  }
}

// =================== sched: tile descriptors + load-balance loss ===================
__global__ void sched_kernel(const int* __restrict__ cnt,
                             const float* __restrict__ usage,
                             int* __restrict__ ntiles,
                             int2* __restrict__ desc,
                             float* __restrict__ out_loss) {
  int lane = threadIdx.x;
  int e = lane & 15;
  int c = (lane < 16) ? cnt[e] : 0;
  int tl = (c + 127) >> 7;
  int v = tl;
#pragma unroll
  for (int d = 1; d < 16; d <<= 1) {
    int u = __shfl_up(v, d);
    if (lane >= d) v += u;
  }
  int excl = v - tl;
  int tot = __shfl(v, 15);
  if (lane == 0) *ntiles = tot;
  if (lane < 16) {
    for (int i = 0; i < tl; ++i) desc[excl + i] = make_int2(e, i << 7);
    float d0 = usage[e] * (1.f / 4096.f) - (1.f / 16.f);
    float ls = d0 * d0;
#pragma unroll
    for (int d = 1; d < 16; d <<= 1) ls += __shfl_xor(ls, d);
    if (lane == 0) *out_loss = ls * (1.f / 16.f);
  }
}

// =================== gather: build A bf16 chunk-major [ty][kc8][128][64] ===================
__launch_bounds__(256)
__global__ void gather_kernel(const float* __restrict__ x,
                              const int* __restrict__ cnt,
                              const int* __restrict__ ntiles,
                              const int2* __restrict__ desc,
                              const int* __restrict__ lists,
                              unsigned short* __restrict__ G) {
  int ty = blockIdx.x;
  if (ty >= *ntiles) return;
  int2 dd = desc[ty];
  int e = dd.x, i0 = dd.y;
  int cntE = cnt[e];
  int tid = threadIdx.x, r = tid >> 1, h = tid & 1;
  int aidx = i0 + r;
  bool valid = aidx < cntE;
  int slot = valid ? lists[e * CAP + aidx] : 0;
  const float* xrow = x + (size_t)(slot >> 1) * DIM;
  unsigned short* gb = G + (size_t)ty * 65536;
#pragma unroll
  for (int c4 = 0; c4 < 4; ++c4) {
    int chunk = h * 4 + c4;
    unsigned short* dst = gb + (size_t)chunk * 8192 + r * 64;
#pragma unroll
    for (int j = 0; j < 8; ++j) {
      u16x8 pk;
      if (valid) {
        float4 u = *(const float4*)(xrow + chunk * 64 + j * 8);
        float4 w = *(const float4*)(xrow + chunk * 64 + j * 8 + 4);
        pk[0] = f2bf(u.x); pk[1] = f2bf(u.y); pk[2] = f2bf(u.z); pk[3] = f2bf(u.w);
        pk[4] = f2bf(w.x); pk[5] = f2bf(w.y); pk[6] = f2bf(w.z); pk[7] = f2bf(w.w);
      } else {
        pk = u16x8{0, 0, 0, 0, 0, 0, 0, 0};
      }
      *(u16x8*)(dst + j * 8) = pk;
    }
  }
}

// =================== up GEMM: G @ T_up -> gelu -> hid (bf16 chunk-major) ===================
// BM=128 BN=128 BK=64, 4 waves (2x2), double-buffered global_load_lds, 2-phase.
__launch_bounds__(256)
__global__ void up_kernel(const unsigned short* __restrict__ G,
                          const unsigned short* __restrict__ Tup,
                          const float* __restrict__ up_b,
                          const int* __restrict__ ntiles,
                          const int2* __restrict__ desc,
                          unsigned short* __restrict__ hid) {
  int ty = blockIdx.y;
  if (ty >= *ntiles) return;
  int e = desc[ty].x;
  int f0 = blockIdx.x * 128;
  __shared__ __align__(16) unsigned short Ab[2][128 * 64];
  __shared__ __align__(16) unsigned short Bb[2][128 * 64];
  int tid = threadIdx.x, lane = tid & 63, wid = tid >> 6;
  const unsigned short* Asrc = G + (size_t)ty * 65536;                    // + kc*8192
  const unsigned short* Bsrc = Tup + ((size_t)(e * 8) * FF + f0) * 64;    // + kc*FF*64

  int wr = wid >> 1, wc = wid & 1, ln15 = lane & 15, lq = lane >> 4;
  f32x4 acc[4][4];
#pragma unroll
  for (int i = 0; i < 4; ++i)
#pragma unroll
    for (int j = 0; j < 4; ++j) acc[i][j] = f32x4{0.f, 0.f, 0.f, 0.f};

#define UP_STAGE(b, kc) do {                                          \
    const unsigned short* a_ = Asrc + (size_t)(kc) * 8192;            \
    const unsigned short* b_ = Bsrc + (size_t)(kc) * FF * 64;         \
    _Pragma("unroll")                                                 \
    for (int i_ = 0; i_ < 4; ++i_) {                                  \
      int off_ = (wid * 4 + i_) * 512;                                \
      GLOAD16(a_ + off_ + lane * 8, &Ab[b][off_]);                    \
      GLOAD16(b_ + off_ + lane * 8, &Bb[b][off_]);                    \
    }                                                                 \
  } while (0)

  UP_STAGE(0, 0);
  asm volatile("s_waitcnt vmcnt(0)" ::: "memory");
  __syncthreads();
  int cur = 0;
  for (int kc = 0; kc < 8; ++kc) {
    if (kc < 7) UP_STAGE(cur ^ 1, kc + 1);
    const unsigned short* As = Ab[cur];
    const unsigned short* Bs = Bb[cur];
#pragma unroll
    for (int ksub = 0; ksub < 2; ++ksub) {
      bf16x8 a[4], b[4];
      int g = (ksub << 2) + lq;
#pragma unroll
      for (int mi = 0; mi < 4; ++mi)
        a[mi] = *(const bf16x8*)(As + ((wr << 6) + (mi << 4) + ln15) * 64 + (g << 3));
#pragma unroll
      for (int ni = 0; ni < 4; ++ni)
        b[ni] = *(const bf16x8*)(Bs + ((wc << 6) + (ni << 4) + ln15) * 64 + (g << 3));
#pragma unroll
      for (int mi = 0; mi < 4; ++mi)
#pragma unroll
        for (int ni = 0; ni < 4; ++ni)
          acc[mi][ni] = __builtin_amdgcn_mfma_f32_16x16x32_bf16(a[mi], b[ni], acc[mi][ni], 0, 0, 0);
    }
    asm volatile("s_waitcnt vmcnt(0)" ::: "memory");
    __syncthreads();
    cur ^= 1;
  }
  // epilogue: bias + exact gelu -> hid chunk-major [ty*32 + f/64][row][64]
#pragma unroll
  for (int mi = 0; mi < 4; ++mi) {
    int row = (wr << 6) + (mi << 4) + (lq << 2);
#pragma unroll
    for (int ni = 0; ni < 4; ++ni) {
      int col = (wc << 6) + (ni << 4) + ln15;      // 0..127
      float bias = up_b[e * FF + f0 + col];
      size_t base = ((size_t)(ty * 32 + (f0 >> 6) + (col >> 6)) * 128 + row) * 64 + (col & 63);
#pragma unroll
      for (int q = 0; q < 4; ++q) {
        float vv = acc[mi][ni][q] + bias;
        float gl = 0.5f * vv * (1.f + erff(vv * 0.70710678118f));
        hid[base + (size_t)q * 64] = f2bf(gl);
      }
    }
  }
#undef UP_STAGE
}

// =================== down GEMM: hid @ T_dn -> pairbuf (fp32 scatter) ===================
// BM=128 BN=64 BK=64, 4 waves (2x2), 32 k-chunks, 2-phase.
__launch_bounds__(256)
__global__ void down_kernel(const unsigned short* __restrict__ hid,
                            const unsigned short* __restrict__ Tdn,
                            const float* __restrict__ down_b,
                            const int* __restrict__ cnt,
                            const int* __restrict__ ntiles,
                            const int2* __restrict__ desc,
                            const int* __restrict__ lists,
                            float* __restrict__ pairbuf) {
  int ty = blockIdx.y;
  if (ty >= *ntiles) return;
  int2 dd = desc[ty];
  int e = dd.x, i0 = dd.y;
  int cntE = cnt[e];
  int n0 = blockIdx.x * 64;
  __shared__ __align__(16) unsigned short Ab[2][128 * 64];
  __shared__ __align__(16) unsigned short Bb[2][64 * 64];
  int tid = threadIdx.x, lane = tid & 63, wid = tid >> 6;
  const unsigned short* Asrc = hid + (size_t)ty * 32 * 8192;              // + kc*8192
  const unsigned short* Bsrc = Tdn + ((size_t)(e * 32) * DIM + n0) * 64;  // + kc*DIM*64

  int wr = wid >> 1, wc = wid & 1, ln15 = lane & 15, lq = lane >> 4;
  f32x4 acc[4][2];
#pragma unroll
  for (int i = 0; i < 4; ++i) { acc[i][0] = f32x4{0.f,0.f,0.f,0.f}; acc[i][1] = f32x4{0.f,0.f,0.f,0.f}; }

#define DN_STAGE(b, kc) do {                                          \
    const unsigned short* a_ = Asrc + (size_t)(kc) * 8192;            \
    const unsigned short* b_ = Bsrc + (size_t)(kc) * DIM * 64;        \
    _Pragma("unroll")                                                 \
    for (int i_ = 0; i_ < 4; ++i_) {                                  \
      int off_ = (wid * 4 + i_) * 512;                                \
      GLOAD16(a_ + off_ + lane * 8, &Ab[b][off_]);                    \
    }                                                                 \
    _Pragma("unroll")                                                 \
    for (int i_ = 0; i_ < 2; ++i_) {                                  \
      int off_ = (wid * 2 + i_) * 512;                                \
      GLOAD16(b_ + off_ + lane * 8, &Bb[b][off_]);                    \
    }                                                                 \
  } while (0)

  DN_STAGE(0, 0);
  asm volatile("s_waitcnt vmcnt(0)" ::: "memory");
  __syncthreads();
  int cur = 0;
  for (int kc = 0; kc < 32; ++kc) {
    if (kc < 31) DN_STAGE(cur ^ 1, kc + 1);
    const unsigned short* As = Ab[cur];
    const unsigned short* Bs = Bb[cur];
#pragma unroll
    for (int ksub = 0; ksub < 2; ++ksub) {
      bf16x8 a[4], b[2];
      int g = (ksub << 2) + lq;
#pragma unroll
      for (int mi = 0; mi < 4; ++mi)
        a[mi] = *(const bf16x8*)(As + ((wr << 6) + (mi << 4) + ln15) * 64 + (g << 3));
#pragma unroll
      for (int ni = 0; ni < 2; ++ni)
        b[ni] = *(const bf16x8*)(Bs + ((wc << 5) + (ni << 4) + ln15) * 64 + (g << 3));
#pragma unroll
      for (int mi = 0; mi < 4; ++mi)
#pragma unroll
        for (int ni = 0; ni < 2; ++ni)
          acc[mi][ni] = __builtin_amdgcn_mfma_f32_16x16x32_bf16(a[mi], b[ni], acc[mi][ni], 0, 0, 0);
    }
    asm volatile("s_waitcnt vmcnt(0)" ::: "memory");
    __syncthreads();
    cur ^= 1;
  }
  // epilogue: bias + scatter rows via lists
#pragma unroll
  for (int mi = 0; mi < 4; ++mi) {
    int row = (wr << 6) + (mi << 4) + (lq << 2);
#pragma unroll
    for (int ni = 0; ni < 2; ++ni) {
      int col = n0 + (wc << 5) + (ni << 4) + ln15;
      float bias = down_b[e * DIM + col];
#pragma unroll
      for (int q = 0; q < 4; ++q) {
        int idx = i0 + row + q;
        if (idx < cntE) {
          int slot = lists[e * CAP + idx];
          pairbuf[(size_t)slot * DIM + col] = acc[mi][ni][q] + bias;
        }
      }
    }
  }
#undef DN_STAGE
}

// =================== combine: out[t] = w0*pair[2t] + w1*pair[2t+1] ===================
__launch_bounds__(256)
__global__ void combine_kernel(const float* __restrict__ pairbuf,
                               const float* __restrict__ wts,
                               float* __restrict__ out) {
  int t = blockIdx.x;
  int d = threadIdx.x << 1;
  float w0 = wts[2 * t], w1 = wts[2 * t + 1];
  float2 a = *(const float2*)(pairbuf + (size_t)(2 * t) * DIM + d);
  float2 b = *(const float2*)(pairbuf + (size_t)(2 * t + 1) * DIM + d);
  float2 r; r.x = w0 * a.x + w1 * b.x; r.y = w0 * a.y + w1 * b.y;
  *(float2*)(out + (size_t)t * DIM + d) = r;
}

extern "C" void kernel_launch(void* const* d_in, const int* in_sizes, int n_in,
                              void* d_out, int out_size, void* d_ws, size_t ws_size,
                              hipStream_t stream) {
  (void)in_sizes; (void)n_in; (void)out_size; (void)ws_size;
  const float* x   = (const float*)d_in[0];
  const float* gw1 = (const float*)d_in[1];
  const float* gb1 = (const float*)d_in[2];
  const float* gw2 = (const float*)d_in[3];
  const float* gb2 = (const float*)d_in[4];
  const float* uw  = (const float*)d_in[5];
  const float* ub  = (const float*)d_in[6];
  const float* dw  = (const float*)d_in[7];
  const float* db  = (const float*)d_in[8];
  float* out = (float*)d_out;
  char* ws = (char*)d_ws;

  int*   cnt     = (int*)(ws + WS_CNT);
  float* usage   = (float*)(ws + WS_USAGE);
  int*   ntiles  = (int*)(ws + WS_NTILES);
  int2*  desc    = (int2*)(ws + WS_DESC);
  float* wts     = (float*)(ws + WS_WTS);
  int*   lists   = (int*)(ws + WS_LISTS);
  float* H       = (float*)(ws + WS_H);
  unsigned short* G   = (unsigned short*)(ws + WS_G);
  unsigned short* Tup = (unsigned short*)(ws + WS_TUP);
  unsigned short* Tdn = (unsigned short*)(ws + WS_TDN);
  unsigned short* hid = (unsigned short*)(ws + WS_HID);
  float* pairbuf = (float*)(ws + WS_PAIR);

  hipMemsetAsync(d_ws, 0, 1024, stream);  // zero cnt/usage/ntiles
  fused0_kernel<<<2560, 256, 0, stream>>>(x, gw1, gb1, uw, dw, H, Tup, Tdn);
  score_kernel<<<NTOK / 16, 256, 0, stream>>>(H, gw2, gb2, out, cnt, usage, wts, lists);
  sched_kernel<<<1, 64, 0, stream>>>(cnt, usage, ntiles, desc, out + OUT_LOSS);
  gather_kernel<<<MAXTILES, 256, 0, stream>>>(x, cnt, ntiles, desc, lists, G);
  up_kernel<<<dim3(FF / 128, MAXTILES), 256, 0, stream>>>(G, Tup, ub, ntiles, desc, hid);
  down_kernel<<<dim3(DIM / 64, MAXTILES), 256, 0, stream>>>(hid, Tdn, db, cnt, ntiles, desc, lists, pairbuf);
  combine_kernel<<<NTOK, 256, 0, stream>>>(pairbuf, wts, out);
}

// Round 5
// 363.761 us; speedup vs baseline: 1.1746x; 1.0418x over previous
//
#include <hip/hip_runtime.h>
#include <hip/hip_bf16.h>

// Problem constants
#define NTOK 4096      // B*S
#define DIM  512       // D
#define DH   256       // D/2
#define NE   16        // experts
#define FF   2048      // F
#define CAP  8192      // per-expert list capacity
#define MAXTILES 80    // sum ceil(cnt_e/128) <= 79
#define TEMP_INV 2.0f  // 1/temperature

// out layout: [NTOK*DIM output][1 loss][NTOK*NE probs]
#define OUT_LOSS  (NTOK * DIM)
#define OUT_PROBS (NTOK * DIM + 1)

// ws layout (bytes). Temporal reuse:
//   H (4MB, dead after score) and G (10MB, written after) share [1MB..).
//   pairbuf (16MB, written by down) reuses Tup region (dead after up).
#define WS_CNT    0            // int[16]
#define WS_USAGE  64           // float[16]
#define WS_NTILES 128          // int
#define WS_DESC   256          // int2[80]
#define WS_WTS    1024         // float[2*NTOK]
#define WS_LISTS  36864        // int[16*CAP] (512KB)
#define WS_H      (1ull<<20)   // fp32 [4096][256] = 4MB
#define WS_G      (1ull<<20)   // bf16 [80][8][128][64] = 10MB (swizzled granules)
#define WS_TUP    (16ull<<20)  // bf16 [16*8][2048][64] = 32MB (swizzled granules)
#define WS_PAIR   (16ull<<20)  // fp32 [8192][512] = 16MB (after Tup dead)
#define WS_TDN    (48ull<<20)  // bf16 [16*32][512][64] = 32MB (swizzled granules)
#define WS_HID    (80ull<<20)  // bf16 [80*32][128][64] = 40MB (swizzled granules)

typedef __attribute__((ext_vector_type(8))) short bf16x8;           // MFMA A/B frag
typedef __attribute__((ext_vector_type(8))) unsigned short u16x8;   // 8 bf16 storage
typedef __attribute__((ext_vector_type(4))) float f32x4;            // MFMA C/D frag

__device__ __forceinline__ unsigned short f2bf(float f) {  // RNE f32->bf16
  union { float f; unsigned u; } c; c.f = f;
  return (unsigned short)((c.u + 0x7FFFu + ((c.u >> 16) & 1u)) >> 16);
}

// async global->LDS, 16B per lane. LDS dest = wave-uniform base + lane*16.
#define GLOAD16(gp, lp) __builtin_amdgcn_global_load_lds( \
    (const __attribute__((address_space(1))) void*)(gp), \
    (__attribute__((address_space(3))) void*)(lp), 16, 0, 0)

// =================== prep: router-h GEMM (512 blk) + weight convert/transpose (8192 blk) ===================
// 64-thread blocks.
// bx < 512: router h = relu(x@w1+b1) -> H. [64tok][32col] per block, 8x4/thread.
// bx in [512, 4608):   up_w fp32 [e][512k][2048f] -> Tup bf16 [e*8+kc][2048f][64k], XOR-swizzled granules
// bx in [4608, 8704): down_w fp32 [e][2048k][512d] -> Tdn bf16 [e*32+kc][512d][64k], XOR-swizzled granules
__launch_bounds__(64)
__global__ void prep_kernel(const float* __restrict__ x,
                            const float* __restrict__ w1,
                            const float* __restrict__ b1,
                            const float* __restrict__ up_w,
                            const float* __restrict__ down_w,
                            float* __restrict__ H,
                            unsigned short* __restrict__ Tup,
                            unsigned short* __restrict__ Tdn) {
  __shared__ __align__(16) float As[32 * 72];  // [32k][64tok pad72]
  __shared__ __align__(16) float Bs[32 * 40];  // [32k][32col pad40]
  int bx = blockIdx.x, tid = threadIdx.x;

  if (bx < 512) {
    int tok0 = (bx >> 3) * 64, n0 = (bx & 7) * 32;
    int ty = tid >> 3, tx = tid & 7;           // 8x8 threads; tile 8tok x 4col
    float acc[8][4];
#pragma unroll
    for (int r = 0; r < 8; ++r)
#pragma unroll
      for (int c = 0; c < 4; ++c) acc[r][c] = 0.f;

    for (int kc = 0; kc < 16; ++kc) {
      int k0 = kc * 32;
      // stage A: x[tok0+tid][k0..k0+32) -> As[k][tid] (transposed)
      {
        const float* xp = x + (size_t)(tok0 + tid) * DIM + k0;
#pragma unroll
        for (int q = 0; q < 8; ++q) {
          float4 v = *(const float4*)(xp + q * 4);
          As[(q * 4 + 0) * 72 + tid] = v.x;
          As[(q * 4 + 1) * 72 + tid] = v.y;
          As[(q * 4 + 2) * 72 + tid] = v.z;
          As[(q * 4 + 3) * 72 + tid] = v.w;
        }
      }
      // stage B: w1[k0+k][n0..n0+32) -> Bs[k][n] (no transpose)
      {
        int kk = tid >> 1, ns = (tid & 1) * 16;
#pragma unroll
        for (int j = 0; j < 4; ++j)
          *(float4*)&Bs[kk * 40 + ns + j * 4] =
              *(const float4*)(w1 + (size_t)(k0 + kk) * DH + n0 + ns + j * 4);
      }
      __syncthreads();
#pragma unroll 8
      for (int k = 0; k < 32; ++k) {
        float4 a0 = *(const float4*)&As[k * 72 + ty * 8];
        float4 a1 = *(const float4*)&As[k * 72 + ty * 8 + 4];
        float4 b  = *(const float4*)&Bs[k * 40 + tx * 4];
#pragma unroll
        for (int c = 0; c < 4; ++c) {
          float bv = (c == 0) ? b.x : (c == 1) ? b.y : (c == 2) ? b.z : b.w;
          acc[0][c] = fmaf(a0.x, bv, acc[0][c]);
          acc[1][c] = fmaf(a0.y, bv, acc[1][c]);
          acc[2][c] = fmaf(a0.z, bv, acc[2][c]);
          acc[3][c] = fmaf(a0.w, bv, acc[3][c]);
          acc[4][c] = fmaf(a1.x, bv, acc[4][c]);
          acc[5][c] = fmaf(a1.y, bv, acc[5][c]);
          acc[6][c] = fmaf(a1.z, bv, acc[6][c]);
          acc[7][c] = fmaf(a1.w, bv, acc[7][c]);
        }
      }
      __syncthreads();
    }
    float4 bb = *(const float4*)(b1 + n0 + tx * 4);
#pragma unroll
    for (int r = 0; r < 8; ++r) {
      float4 o;
      o.x = fmaxf(acc[r][0] + bb.x, 0.f);
      o.y = fmaxf(acc[r][1] + bb.y, 0.f);
      o.z = fmaxf(acc[r][2] + bb.z, 0.f);
      o.w = fmaxf(acc[r][3] + bb.w, 0.f);
      *(float4*)(H + (size_t)(tok0 + ty * 8 + r) * DH + n0 + tx * 4) = o;
    }
  } else {
    // ---- direct-gather transpose convert: no LDS ----
    int cb = bx - 512;
    const float* src; unsigned short* dst; int stride;
    if (cb < 4096) {
      int e = cb >> 8, kc = (cb >> 5) & 7, nb = cb & 31;
      src = up_w + (size_t)e * DIM * FF + (size_t)kc * 64 * FF + nb * 64;
      dst = Tup + ((size_t)(e * 8 + kc) * FF + nb * 64) * 64;
      stride = FF;
    } else {
      cb -= 4096;
      int e = cb >> 8, kc = (cb >> 3) & 31, nb = cb & 7;
      src = down_w + (size_t)e * FF * DIM + (size_t)kc * 64 * DIM + nb * 64;
      dst = Tdn + ((size_t)(e * 32 + kc) * DIM + nb * 64) * 64;
      stride = DIM;
    }
    // thread owns output row n = tid: reads 64 k-strided floats (wave-coalesced
    // 256B per k-row), writes one 128B row as 8 swizzled 16B granules.
    const float* s = src + tid;
    unsigned short* drow = dst + (size_t)tid * 64;
    int sx = tid & 7;
#pragma unroll
    for (int g = 0; g < 8; ++g) {
      u16x8 pk;
#pragma unroll
      for (int j = 0; j < 8; ++j) pk[j] = f2bf(s[(size_t)(g * 8 + j) * stride]);
      *(u16x8*)(drow + ((g ^ sx) << 3)) = pk;
    }
  }
}

// =================== score: softmax + top2 + lists (per 16 tokens) ===================
__launch_bounds__(256)
__global__ void score_kernel(const float* __restrict__ H,
                             const float* __restrict__ w2,
                             const float* __restrict__ b2,
                             float* __restrict__ out,
                             int* __restrict__ cnt,
                             float* __restrict__ usage,
                             float* __restrict__ wts,
                             int* __restrict__ lists) {
  __shared__ __align__(16) float hs[16][260];
  __shared__ __align__(16) float w2t[16][260];
  __shared__ float ps[16][NE];
  __shared__ float us[4][NE];
  int tid = threadIdx.x;
  int tok0 = blockIdx.x * 16;
  {
    int r = tid >> 4, seg = tid & 15;
    const float* hp = H + (size_t)(tok0 + r) * DH + seg * 16;
    *(float4*)&hs[r][seg * 16 + 0]  = *(const float4*)(hp + 0);
    *(float4*)&hs[r][seg * 16 + 4]  = *(const float4*)(hp + 4);
    *(float4*)&hs[r][seg * 16 + 8]  = *(const float4*)(hp + 8);
    *(float4*)&hs[r][seg * 16 + 12] = *(const float4*)(hp + 12);
  }
  {
    float4 a = *(const float4*)(w2 + (size_t)tid * 16 + 0);
    float4 b = *(const float4*)(w2 + (size_t)tid * 16 + 4);
    float4 c = *(const float4*)(w2 + (size_t)tid * 16 + 8);
    float4 d = *(const float4*)(w2 + (size_t)tid * 16 + 12);
    w2t[0][tid] = a.x;  w2t[1][tid] = a.y;  w2t[2][tid] = a.z;  w2t[3][tid] = a.w;
    w2t[4][tid] = b.x;  w2t[5][tid] = b.y;  w2t[6][tid] = b.z;  w2t[7][tid] = b.w;
    w2t[8][tid] = c.x;  w2t[9][tid] = c.y;  w2t[10][tid] = c.z; w2t[11][tid] = c.w;
    w2t[12][tid] = d.x; w2t[13][tid] = d.y; w2t[14][tid] = d.z; w2t[15][tid] = d.w;
  }
  __syncthreads();
  int t = tid >> 4, e = tid & 15;
  float s = b2[e];
#pragma unroll 4
  for (int j4 = 0; j4 < 64; ++j4) {
    float4 hv = *(const float4*)&hs[t][j4 * 4];
    float4 wv = *(const float4*)&w2t[e][j4 * 4];
    s = fmaf(hv.x, wv.x, fmaf(hv.y, wv.y, fmaf(hv.z, wv.z, fmaf(hv.w, wv.w, s))));
  }
  s *= TEMP_INV;
  float m = s;
#pragma unroll
  for (int d = 1; d < 16; d <<= 1) m = fmaxf(m, __shfl_xor(m, d));
  float p = expf(s - m);
  float sum = p;
#pragma unroll
  for (int d = 1; d < 16; d <<= 1) sum += __shfl_xor(sum, d);
  float prob = p / sum;
  out[OUT_PROBS + (size_t)(tok0 + t) * NE + e] = prob;
  ps[t][e] = prob;
  float v = prob;
  v += __shfl_xor(v, 16);
  v += __shfl_xor(v, 32);
  if ((tid & 63) < 16) us[tid >> 6][e] = v;
  __syncthreads();
  if (tid < 16) atomicAdd(&usage[tid], us[0][tid] + us[1][tid] + us[2][tid] + us[3][tid]);

  if (tid < 16) {
    int tt = tid;
    float v1 = -1.f; int i1 = 0;
    for (int ee = 0; ee < NE; ++ee) { float pv = ps[tt][ee]; if (pv > v1) { v1 = pv; i1 = ee; } }
    float v2 = -1.f; int i2 = 0;
    for (int ee = 0; ee < NE; ++ee) { if (ee == i1) continue; float pv = ps[tt][ee]; if (pv > v2) { v2 = pv; i2 = ee; } }
    float mm = fmaxf(v1, v2);
    float e0 = expf(v1 - mm), e1 = expf(v2 - mm);
    float rs = 1.f / (e0 + e1);
    int gt = tok0 + tt;
    wts[2 * gt]     = e0 * rs;
    wts[2 * gt + 1] = e1 * rs;
    int p1 = atomicAdd(&cnt[i1], 1);
    lists[i1 * CAP + p1] = 2 * gt;
    int p2 = atomicAdd(&cnt[i2], 1);
    lists[i2 * CAP + p2] = 2 * gt + 1;
  }
}

// =================== sched: tile descriptors + load-balance loss ===================
__global__ void sched_kernel(const int* __restrict__ cnt,
                             const float* __restrict__ usage,
                             int* __restrict__ ntiles,
                             int2* __restrict__ desc,
                             float* __restrict__ out_loss) {
  int lane = threadIdx.x;
  int e = lane & 15;
  int c = (lane < 16) ? cnt[e] : 0;
  int tl = (c + 127) >> 7;
  int v = tl;
#pragma unroll
  for (int d = 1; d < 16; d <<= 1) {
    int u = __shfl_up(v, d);
    if (lane >= d) v += u;
  }
  int excl = v - tl;
  int tot = __shfl(v, 15);
  if (lane == 0) *ntiles = tot;
  if (lane < 16) {
    for (int i = 0; i < tl; ++i) desc[excl + i] = make_int2(e, i << 7);
    float d0 = usage[e] * (1.f / 4096.f) - (1.f / 16.f);
    float ls = d0 * d0;
#pragma unroll
    for (int d = 1; d < 16; d <<= 1) ls += __shfl_xor(ls, d);
    if (lane == 0) *out_loss = ls * (1.f / 16.f);
  }
}

// =================== gather: build A bf16 chunk-major [ty][kc8][128][64], swizzled ===================
__launch_bounds__(256)
__global__ void gather_kernel(const float* __restrict__ x,
                              const int* __restrict__ cnt,
                              const int* __restrict__ ntiles,
                              const int2* __restrict__ desc,
                              const int* __restrict__ lists,
                              unsigned short* __restrict__ G) {
  int ty = blockIdx.x;
  if (ty >= *ntiles) return;
  int2 dd = desc[ty];
  int e = dd.x, i0 = dd.y;
  int cntE = cnt[e];
  int tid = threadIdx.x, r = tid >> 1, h = tid & 1;
  int aidx = i0 + r;
  bool valid = aidx < cntE;
  int slot = valid ? lists[e * CAP + aidx] : 0;
  const float* xrow = x + (size_t)(slot >> 1) * DIM;
  int chunk = blockIdx.y * 2 + h;
  unsigned short* dst = G + (size_t)ty * 65536 + (size_t)chunk * 8192 + r * 64;
  int sx = r & 7;
#pragma unroll
  for (int j = 0; j < 8; ++j) {
    u16x8 pk;
    if (valid) {
      float4 u = *(const float4*)(xrow + chunk * 64 + j * 8);
      float4 w = *(const float4*)(xrow + chunk * 64 + j * 8 + 4);
      pk[0] = f2bf(u.x); pk[1] = f2bf(u.y); pk[2] = f2bf(u.z); pk[3] = f2bf(u.w);
      pk[4] = f2bf(w.x); pk[5] = f2bf(w.y); pk[6] = f2bf(w.z); pk[7] = f2bf(w.w);
    } else {
      pk = u16x8{0, 0, 0, 0, 0, 0, 0, 0};
    }
    *(u16x8*)(dst + ((j ^ sx) << 3)) = pk;
  }
}

// =================== up GEMM: G @ Tup -> gelu -> hid (bf16, swizzled granules) ===================
// BM=128 BN=128 BK=64, 4 waves (2x2), double-buffered global_load_lds, 2-phase.
__launch_bounds__(256)
__global__ void up_kernel(const unsigned short* __restrict__ G,
                          const unsigned short* __restrict__ Tup,
                          const float* __restrict__ up_b,
                          const int* __restrict__ ntiles,
                          const int2* __restrict__ desc,
                          unsigned short* __restrict__ hid) {
  int ty = blockIdx.y;
  if (ty >= *ntiles) return;
  int e = desc[ty].x;
  int f0 = blockIdx.x * 128;
  __shared__ __align__(16) unsigned short smem[32768];   // 64KB: A0 A1 B0 B1 (8192 each)
  int tid = threadIdx.x, lane = tid & 63, wid = tid >> 6;
  const unsigned short* Asrc = G + (size_t)ty * 65536;                    // + kc*8192
  const unsigned short* Bsrc = Tup + ((size_t)(e * 8) * FF + f0) * 64;    // + kc*FF*64

  int wr = wid >> 1, wc = wid & 1, ln15 = lane & 15, lq = lane >> 4;
  f32x4 acc[4][4];
#pragma unroll
  for (int i = 0; i < 4; ++i)
#pragma unroll
    for (int j = 0; j < 4; ++j) acc[i][j] = f32x4{0.f, 0.f, 0.f, 0.f};

#define UP_STAGE(b, kc) do {                                          \
    const unsigned short* a_ = Asrc + (size_t)(kc) * 8192;            \
    const unsigned short* b_ = Bsrc + (size_t)(kc) * FF * 64;         \
    unsigned short* al_ = smem + (b) * 8192;                          \
    unsigned short* bl_ = smem + 16384 + (b) * 8192;                  \
    _Pragma("unroll")                                                 \
    for (int i_ = 0; i_ < 4; ++i_) {                                  \
      int off_ = (wid * 4 + i_) * 512;                                \
      GLOAD16(a_ + off_ + lane * 8, al_ + off_ + lane * 8);           \
      GLOAD16(b_ + off_ + lane * 8, bl_ + off_ + lane * 8);           \
    }                                                                 \
  } while (0)

  UP_STAGE(0, 0);
  asm volatile("s_waitcnt vmcnt(0)" ::: "memory");
  __syncthreads();
  int cur = 0;
  for (int kc = 0; kc < 8; ++kc) {
    if (kc < 7) UP_STAGE(cur ^ 1, kc + 1);
    const unsigned short* As = smem + cur * 8192;
    const unsigned short* Bs = smem + 16384 + cur * 8192;
#pragma unroll
    for (int ksub = 0; ksub < 2; ++ksub) {
      bf16x8 a[4], b[4];
      int g = (ksub << 2) + lq;
      int sw = (g ^ (ln15 & 7)) << 3;   // XOR-swizzled granule slot
#pragma unroll
      for (int mi = 0; mi < 4; ++mi)
        a[mi] = *(const bf16x8*)(As + ((wr << 6) + (mi << 4) + ln15) * 64 + sw);
#pragma unroll
      for (int ni = 0; ni < 4; ++ni)
        b[ni] = *(const bf16x8*)(Bs + ((wc << 6) + (ni << 4) + ln15) * 64 + sw);
#pragma unroll
      for (int mi = 0; mi < 4; ++mi)
#pragma unroll
        for (int ni = 0; ni < 4; ++ni)
          acc[mi][ni] = __builtin_amdgcn_mfma_f32_16x16x32_bf16(a[mi], b[ni], acc[mi][ni], 0, 0, 0);
    }
    asm volatile("s_waitcnt vmcnt(0)" ::: "memory");
    __syncthreads();
    cur ^= 1;
  }
  // epilogue: bias + exact gelu -> LDS transpose -> vectorized swizzled hid stores
  unsigned short* Cs = smem;  // [128][136] u16 = 34.8KB (reuses A/B buffers)
#pragma unroll
  for (int mi = 0; mi < 4; ++mi) {
#pragma unroll
    for (int ni = 0; ni < 4; ++ni) {
      int col = (wc << 6) + (ni << 4) + ln15;
      float bias = up_b[e * FF + f0 + col];
#pragma unroll
      for (int q = 0; q < 4; ++q) {
        int row = (wr << 6) + (mi << 4) + (lq << 2) + q;
        float vv = acc[mi][ni][q] + bias;
        float gl = 0.5f * vv * (1.f + erff(vv * 0.70710678118f));
        Cs[row * 136 + col] = f2bf(gl);
      }
    }
  }
  __syncthreads();
#pragma unroll
  for (int i = 0; i < 8; ++i) {
    int seg = tid + i * 256;
    int row = seg >> 4, c16 = seg & 15;
    int chunk = ty * 32 + (f0 >> 6) + (c16 >> 3);
    int slot = (c16 & 7) ^ (row & 7);
    u16x8 v = *(const u16x8*)(Cs + row * 136 + c16 * 8);
    *(u16x8*)(hid + ((size_t)chunk * 128 + row) * 64 + (slot << 3)) = v;
  }
#undef UP_STAGE
}

// =================== down GEMM: hid @ Tdn -> pairbuf (fp32 scatter) ===================
// BM=128 BN=64 BK=64, 4 waves (2x2), 32 k-chunks, 2-phase.
__launch_bounds__(256)
__global__ void down_kernel(const unsigned short* __restrict__ hid,
                            const unsigned short* __restrict__ Tdn,
                            const float* __restrict__ down_b,
                            const int* __restrict__ cnt,
                            const int* __restrict__ ntiles,
                            const int2* __restrict__ desc,
                            const int* __restrict__ lists,
                            float* __restrict__ pairbuf) {
  int ty = blockIdx.y;
  if (ty >= *ntiles) return;
  int2 dd = desc[ty];
  int e = dd.x, i0 = dd.y;
  int cntE = cnt[e];
  int n0 = blockIdx.x * 64;
  __shared__ __align__(16) unsigned short smem[24576];   // A0 A1 (8192 each) | B0 B1 (4096 each)
  int tid = threadIdx.x, lane = tid & 63, wid = tid >> 6;
  const unsigned short* Asrc = hid + (size_t)ty * 32 * 8192;              // + kc*8192
  const unsigned short* Bsrc = Tdn + ((size_t)(e * 32) * DIM + n0) * 64;  // + kc*DIM*64

  int wr = wid >> 1, wc = wid & 1, ln15 = lane & 15, lq = lane >> 4;
  f32x4 acc[4][2];
#pragma unroll
  for (int i = 0; i < 4; ++i) { acc[i][0] = f32x4{0.f,0.f,0.f,0.f}; acc[i][1] = f32x4{0.f,0.f,0.f,0.f}; }

#define DN_STAGE(b, kc) do {                                          \
    const unsigned short* a_ = Asrc + (size_t)(kc) * 8192;            \
    const unsigned short* b_ = Bsrc + (size_t)(kc) * DIM * 64;        \
    unsigned short* al_ = smem + (b) * 8192;                          \
    unsigned short* bl_ = smem + 16384 + (b) * 4096;                  \
    _Pragma("unroll")                                                 \
    for (int i_ = 0; i_ < 4; ++i_) {                                  \
      int off_ = (wid * 4 + i_) * 512;                                \
      GLOAD16(a_ + off_ + lane * 8, al_ + off_ + lane * 8);           \
    }                                                                 \
    _Pragma("unroll")                                                 \
    for (int i_ = 0; i_ < 2; ++i_) {                                  \
      int off_ = (wid * 2 + i_) * 512;                                \
      GLOAD16(b_ + off_ + lane * 8, bl_ + off_ + lane * 8);           \
    }                                                                 \
  } while (0)

  DN_STAGE(0, 0);
  asm volatile("s_waitcnt vmcnt(0)" ::: "memory");
  __syncthreads();
  int cur = 0;
  for (int kc = 0; kc < 32; ++kc) {
    if (kc < 31) DN_STAGE(cur ^ 1, kc + 1);
    const unsigned short* As = smem + cur * 8192;
    const unsigned short* Bs = smem + 16384 + cur * 4096;
#pragma unroll
    for (int ksub = 0; ksub < 2; ++ksub) {
      bf16x8 a[4], b[2];
      int g = (ksub << 2) + lq;
      int sw = (g ^ (ln15 & 7)) << 3;
#pragma unroll
      for (int mi = 0; mi < 4; ++mi)
        a[mi] = *(const bf16x8*)(As + ((wr << 6) + (mi << 4) + ln15) * 64 + sw);
#pragma unroll
      for (int ni = 0; ni < 2; ++ni)
        b[ni] = *(const bf16x8*)(Bs + ((wc << 5) + (ni << 4) + ln15) * 64 + sw);
#pragma unroll
      for (int mi = 0; mi < 4; ++mi)
#pragma unroll
        for (int ni = 0; ni < 2; ++ni)
          acc[mi][ni] = __builtin_amdgcn_mfma_f32_16x16x32_bf16(a[mi], b[ni], acc[mi][ni], 0, 0, 0);
    }
    asm volatile("s_waitcnt vmcnt(0)" ::: "memory");
    __syncthreads();
    cur ^= 1;
  }
  // epilogue: bias + scatter rows via lists (64B-coalesced per quarter-wave)
#pragma unroll
  for (int mi = 0; mi < 4; ++mi) {
    int row = (wr << 6) + (mi << 4) + (lq << 2);
#pragma unroll
    for (int ni = 0; ni < 2; ++ni) {
      int col = n0 + (wc << 5) + (ni << 4) + ln15;
      float bias = down_b[e * DIM + col];
#pragma unroll
      for (int q = 0; q < 4; ++q) {
        int idx = i0 + row + q;
        if (idx < cntE) {
          int slot = lists[e * CAP + idx];
          pairbuf[(size_t)slot * DIM + col] = acc[mi][ni][q] + bias;
        }
      }
    }
  }
#undef DN_STAGE
}

// =================== combine: out[t] = w0*pair[2t] + w1*pair[2t+1] ===================
__launch_bounds__(256)
__global__ void combine_kernel(const float* __restrict__ pairbuf,
                               const float* __restrict__ wts,
                               float* __restrict__ out) {
  int idx = blockIdx.x * 256 + threadIdx.x;   // one float4 of output
  int t = idx >> 7, d4 = (idx & 127) << 2;
  float w0 = wts[2 * t], w1 = wts[2 * t + 1];
  float4 a = *(const float4*)(pairbuf + (size_t)(2 * t) * DIM + d4);
  float4 b = *(const float4*)(pairbuf + (size_t)(2 * t + 1) * DIM + d4);
  float4 r;
  r.x = w0 * a.x + w1 * b.x; r.y = w0 * a.y + w1 * b.y;
  r.z = w0 * a.z + w1 * b.z; r.w = w0 * a.w + w1 * b.w;
  *(float4*)(out + (size_t)t * DIM + d4) = r;
}

extern "C" void kernel_launch(void* const* d_in, const int* in_sizes, int n_in,
                              void* d_out, int out_size, void* d_ws, size_t ws_size,
                              hipStream_t stream) {
  (void)in_sizes; (void)n_in; (void)out_size; (void)ws_size;
  const float* x   = (const float*)d_in[0];
  const float* gw1 = (const float*)d_in[1];
  const float* gb1 = (const float*)d_in[2];
  const float* gw2 = (const float*)d_in[3];
  const float* gb2 = (const float*)d_in[4];
  const float* uw  = (const float*)d_in[5];
  const float* ub  = (const float*)d_in[6];
  const float* dw  = (const float*)d_in[7];
  const float* db  = (const float*)d_in[8];
  float* out = (float*)d_out;
  char* ws = (char*)d_ws;

  int*   cnt     = (int*)(ws + WS_CNT);
  float* usage   = (float*)(ws + WS_USAGE);
  int*   ntiles  = (int*)(ws + WS_NTILES);
  int2*  desc    = (int2*)(ws + WS_DESC);
  float* wts     = (float*)(ws + WS_WTS);
  int*   lists   = (int*)(ws + WS_LISTS);
  float* H       = (float*)(ws + WS_H);
  unsigned short* G   = (unsigned short*)(ws + WS_G);
  unsigned short* Tup = (unsigned short*)(ws + WS_TUP);
  unsigned short* Tdn = (unsigned short*)(ws + WS_TDN);
  unsigned short* hid = (unsigned short*)(ws + WS_HID);
  float* pairbuf = (float*)(ws + WS_PAIR);

  hipMemsetAsync(d_ws, 0, 1024, stream);  // zero cnt/usage/ntiles
  prep_kernel<<<8704, 64, 0, stream>>>(x, gw1, gb1, uw, dw, H, Tup, Tdn);
  score_kernel<<<NTOK / 16, 256, 0, stream>>>(H, gw2, gb2, out, cnt, usage, wts, lists);
  sched_kernel<<<1, 64, 0, stream>>>(cnt, usage, ntiles, desc, out + OUT_LOSS);
  gather_kernel<<<dim3(MAXTILES, 4), 256, 0, stream>>>(x, cnt, ntiles, desc, lists, G);
  up_kernel<<<dim3(FF / 128, MAXTILES), 256, 0, stream>>>(G, Tup, ub, ntiles, desc, hid);
  down_kernel<<<dim3(DIM / 64, MAXTILES), 256, 0, stream>>>(hid, Tdn, db, cnt, ntiles, desc, lists, pairbuf);
  combine_kernel<<<NTOK * DIM / 4 / 256, 256, 0, stream>>>(pairbuf, wts, out);
}